// Round 11
// baseline (188.262 us; speedup 1.0000x reference)
//
#include <hip/hip_runtime.h>
#include <hip/hip_bf16.h>
#include <string.h>

#define NB   2
#define SEQ  2048
#define EMB  1024
#define NH   16
#define HD   64
// softmax uses exp2: fold SCALE*log2(e) into Q pre-scale
#define QSCALE 0.045084219f       // (1/32) * log2(e)

typedef __attribute__((ext_vector_type(8))) short short8;   // 8 x bf16
typedef __attribute__((ext_vector_type(4))) float f32x4;    // MFMA C/D

#define MFMA(a, b, c) __builtin_amdgcn_mfma_f32_16x16x32_bf16(a, b, c, 0, 0, 0)
#define EXP2(x) __builtin_amdgcn_exp2f(x)

__device__ __forceinline__ unsigned short f2bf(float x) {
    union { float f; unsigned u; } v; v.f = x;
    unsigned r = v.u + 0x7fffu + ((v.u >> 16) & 1u);   // RNE
    return (unsigned short)(r >> 16);
}
__device__ __forceinline__ unsigned packbf2(float a, float b) {
    __hip_bfloat162 h = __float22bfloat162_rn(make_float2(a, b));  // hw v_cvt_pk
    unsigned u; memcpy(&u, &h, 4);
    return u;
}
__device__ __forceinline__ short8 pack8(float4 a, float4 b) {
    unsigned u[4];
    u[0] = packbf2(a.x, a.y); u[1] = packbf2(a.z, a.w);
    u[2] = packbf2(b.x, b.y); u[3] = packbf2(b.z, b.w);
    short8 r; memcpy(&r, u, 16); return r;
}
// async global->LDS, 16B per lane; LDS dest = uniform base + lane*16 (linear)
__device__ __forceinline__ void gload16(const void* g, void* l) {
    __builtin_amdgcn_global_load_lds(
        (const __attribute__((address_space(1))) void*)g,
        (__attribute__((address_space(3))) void*)l, 16, 0, 0);
}

// ---------------------------------------------------------------------------
// Kernel 1 (cvt fused in): per-head QKV projection.
// grid (SEQ/128, NH, 3*NB), block 256.
// Q,K out: [n][h][l][d] bf16 (Q pre-scaled by QSCALE), written via LDS
// transpose + float4 (was: 32 scalar 2-byte stores/thread).  V out:
// [n][h][d][l], masked rows zeroed.  W loaded fp32 + converted in-reg
// (L2-hot) — no separate cvt kernel.  Side work spread across blocks:
// bids<1024 convert one Wo float4/thread; bids 1024..1039 build Mb.
// ---------------------------------------------------------------------------
__global__ __launch_bounds__(256) void qkv_kernel(
    const float* __restrict__ Qin, const float* __restrict__ Kin,
    const float* __restrict__ Vin,
    const float* __restrict__ Wqf, const float* __restrict__ Wkf,
    const float* __restrict__ Wvf, const float* __restrict__ bq,
    const int* __restrict__ mask, const float* __restrict__ Wo,
    unsigned short* __restrict__ Wob, unsigned short* __restrict__ Mb,
    unsigned short* __restrict__ Qp, unsigned short* __restrict__ Kp,
    unsigned short* __restrict__ Vtp)
{
    const int lt = blockIdx.x;          // 128-row l tile
    const int h  = blockIdx.y;
    const int tz = blockIdx.z;
    const int t  = tz >> 1, n = tz & 1;
    const int bid = blockIdx.x + 16 * blockIdx.y + 256 * blockIdx.z;  // 0..1535

    const int tid = threadIdx.x, wave = tid >> 6, lane = tid & 63;
    const int ln = lane & 15, quad = lane >> 4;

    // ---- fused cvt side-work (independent of this block's projection) ----
    if (bid < 1024) {
        int idx = bid * 256 + tid;
        float4 w = ((const float4*)Wo)[idx];
        uint2 p; p.x = packbf2(w.x, w.y); p.y = packbf2(w.z, w.w);
        ((uint2*)Wob)[idx] = p;
    } else if (bid < 1040) {              // 16 blocks x 256 = NB*SEQ = 4096
        int idx = (bid - 1024) * 256 + tid;
        Mb[idx] = mask[idx] ? (unsigned short)0x3F80 : (unsigned short)0;
    }

    const float* X; const float* Wf;
    if (t == 0)      { X = Qin; Wf = Wqf; }
    else if (t == 1) { X = Kin; Wf = Wkf; }
    else             { X = Vin; Wf = Wvf; }

    __shared__ __align__(16) unsigned short sX[128][70];
    __shared__ __align__(16) unsigned short sPool[128 * 72];  // 18432 B
    // overlays: t==2 transpose buffer [64][136]; t<2 output stage [128][72]
    unsigned short (*sT)[136] = (unsigned short(*)[136])sPool;
    unsigned short (*sM)[72]  = (unsigned short(*)[72])sPool;

    #pragma unroll
    for (int i = 0; i < 8; ++i) {
        int flat = tid + i * 256;
        int r = flat >> 4, c4 = flat & 15;
        float4 xv = *(const float4*)(X + ((size_t)(n * SEQ + lt * 128 + r)) * EMB + h * HD + c4 * 4);
        uint2 xp; xp.x = packbf2(xv.x, xv.y); xp.y = packbf2(xv.z, xv.w);
        *(uint2*)&sX[r][c4 * 4] = xp;
    }
    // W fragments: fp32 load + in-reg convert (16 KB/proj, L2-hot)
    short8 wf0[4], wf1[4];
    #pragma unroll
    for (int nt = 0; nt < 4; ++nt) {
        const float* wr = Wf + (nt * 16 + ln) * HD;
        wf0[nt] = pack8(*(const float4*)(wr + quad * 8),
                        *(const float4*)(wr + quad * 8 + 4));
        wf1[nt] = pack8(*(const float4*)(wr + 32 + quad * 8),
                        *(const float4*)(wr + 32 + quad * 8 + 4));
    }
    __syncthreads();

    f32x4 acc[2][4];
    #pragma unroll
    for (int set = 0; set < 2; ++set) {
        short8 af0 = *(const short8*)&sX[wave * 32 + set * 16 + ln][quad * 8];
        short8 af1 = *(const short8*)&sX[wave * 32 + set * 16 + ln][32 + quad * 8];
        #pragma unroll
        for (int nt = 0; nt < 4; ++nt) {
            f32x4 a = {0.f, 0.f, 0.f, 0.f};
            a = MFMA(af0, wf0[nt], a);
            a = MFMA(af1, wf1[nt], a);
            acc[set][nt] = a;
        }
    }

    if (t == 0) {   // bias then fold softmax scale (incl. log2e)
        #pragma unroll
        for (int nt = 0; nt < 4; ++nt) {
            float bb = bq[nt * 16 + ln];
            #pragma unroll
            for (int set = 0; set < 2; ++set)
                #pragma unroll
                for (int a = 0; a < 4; ++a)
                    acc[set][nt][a] = (acc[set][nt][a] + bb) * QSCALE;
        }
    }

    if (t < 2) {
        // stage [l][d] in LDS (2-way-conflict writes = free), then float4 out
        #pragma unroll
        for (int set = 0; set < 2; ++set)
            #pragma unroll
            for (int nt = 0; nt < 4; ++nt)
                #pragma unroll
                for (int a = 0; a < 4; ++a)
                    sM[wave * 32 + set * 16 + quad * 4 + a][nt * 16 + ln] =
                        f2bf(acc[set][nt][a]);
        __syncthreads();
        unsigned short* Out = (t == 0) ? Qp : Kp;
        size_t base = ((size_t)((n * NH + h) * SEQ + lt * 128)) * HD;
        #pragma unroll
        for (int i = 0; i < 4; ++i) {
            int idx = tid + i * 256;          // 1024 float4 = 128 rows x 8
            int r = idx >> 3, c8 = idx & 7;
            *(float4*)(Out + base + (size_t)r * HD + c8 * 8) =
                *(const float4*)&sM[r][c8 * 8];
        }
    } else {
        // zero masked V rows (l = column of V^T)
        #pragma unroll
        for (int set = 0; set < 2; ++set)
            #pragma unroll
            for (int a = 0; a < 4; ++a) {
                int l = lt * 128 + wave * 32 + set * 16 + quad * 4 + a;
                if (mask[n * SEQ + l] == 0) {
                    #pragma unroll
                    for (int nt = 0; nt < 4; ++nt) acc[set][nt][a] = 0.f;
                }
            }
        #pragma unroll
        for (int set = 0; set < 2; ++set)
            #pragma unroll
            for (int nt = 0; nt < 4; ++nt)
                #pragma unroll
                for (int a = 0; a < 4; ++a)
                    sT[nt * 16 + ln][wave * 32 + set * 16 + quad * 4 + a] = f2bf(acc[set][nt][a]);
        __syncthreads();
        #pragma unroll
        for (int i = 0; i < 4; ++i) {
            int flat = tid + i * 256;
            int r = flat >> 4, c8 = flat & 15;
            *(float4*)(Vtp + ((size_t)((n * NH + h) * HD + r)) * SEQ + lt * 128 + c8 * 8) =
                *(const float4*)&sT[r][c8 * 8];
        }
    }
}

// ---------------------------------------------------------------------------
// Kernel 2: flash attention v13 — v12 + s_setprio(1) around the PV MFMA
// cluster (T5; our 2 independent blocks/CU give phase diversity).  Rest
// unchanged from r9/r10 (55.6us): kt-loop unrolled x2 with compile-time
// buffer indices, mask-MFMA denominator, pre-swizzled global_load_lds dbuf.
// grid (NB*NH, SEQ/128), block 256 (4 waves x 32 q-rows).
// ---------------------------------------------------------------------------
__global__ __launch_bounds__(256, 2) void flash_kernel(
    const unsigned short* __restrict__ Qp, const unsigned short* __restrict__ Kp,
    const unsigned short* __restrict__ Vtp, const unsigned short* __restrict__ Mb,
    unsigned short* __restrict__ A /* [n][l][EMB] bf16 */)
{
    const int nh = blockIdx.x;
    const int qt = blockIdx.y;            // 128-row q tile
    const int n  = nh >> 4, h = nh & 15;

    const int tid  = threadIdx.x;
    const int wave = tid >> 6, lane = tid & 63;
    const int ln   = lane & 15, quad = lane >> 4;
    const int ln7  = lane & 7;

    __shared__ __align__(16) unsigned short Kb[2][64 * 64];   // 16 KiB
    __shared__ __align__(16) unsigned short Vb[2][64 * 64];   // 16 KiB
    __shared__ __align__(16) unsigned short sP[4][32 * 64];   // 16 KiB
    unsigned short* sPw = sP[wave];

    // Q B-fragments: wave owns q rows qt*128 + wave*32 + set*16 + ln
    const unsigned short* Qb = Qp + ((size_t)nh * SEQ + qt * 128 + wave * 32) * HD;
    short8 qf[2][2];
    #pragma unroll
    for (int set = 0; set < 2; ++set) {
        qf[set][0] = *(const short8*)(Qb + (set * 16 + ln) * HD + quad * 8);
        qf[set][1] = *(const short8*)(Qb + (set * 16 + ln) * HD + 32 + quad * 8);
    }

    const unsigned short* Kg = Kp  + (size_t)nh * SEQ * HD;
    const unsigned short* Vg = Vtp + (size_t)nh * HD * SEQ;
    const unsigned short* mk = Mb + n * SEQ;

    // loop-invariant swizzled LDS offsets (shorts)
    const int kx0 = ((quad)     ^ ln7) << 3;          // frag col, first half
    const int kx1 = ((quad + 4) ^ ln7) << 3;          // frag col, second half
    const int pw0 = ((quad >> 1) ^ ln7) << 3;         // sP write-chunk base (nt=0)
    const int pwb = (quad & 1) * 4;

    // staging geometry: each gload16 = 1 KiB = 8 rows of 128B.  Wave w stages
    // rows [16w, 16w+16) of both K and V.  Source chunk pre-swizzled so that
    // LDS(row, c) holds global(row, c ^ (row&7)).
    const int r8  = lane >> 3;                       // 0..7
    const int swz = ((lane & 7) ^ r8) << 3;          // shorts within row

    f32x4 o[2][4];
    #pragma unroll
    for (int s2 = 0; s2 < 2; ++s2)
        #pragma unroll
        for (int dt = 0; dt < 4; ++dt) o[s2][dt] = (f32x4){0.f, 0.f, 0.f, 0.f};
    f32x4 ol[2] = {(f32x4){0.f, 0.f, 0.f, 0.f}, (f32x4){0.f, 0.f, 0.f, 0.f}};

    #define STAGE(buf, kt_) do {                                                  \
        const unsigned short* kg_ = Kg + ((size_t)((kt_) * 64 + wave * 16 + r8)) * HD + swz; \
        const unsigned short* vg_ = Vg + ((size_t)(wave * 16 + r8)) * SEQ + (kt_) * 64 + swz; \
        unsigned short* kl_ = &Kb[buf][wave * 16 * 64];                           \
        unsigned short* vl_ = &Vb[buf][wave * 16 * 64];                           \
        gload16(kg_,            kl_);                                             \
        gload16(kg_ + 8 * HD,   kl_ + 8 * 64);                                    \
        gload16(vg_,            vl_);                                             \
        gload16(vg_ + 8 * SEQ,  vl_ + 8 * 64);                                    \
    } while (0)

    // BUF is a compile-time literal -> all LDS addresses fold to static
    // base + offset: immediates (no per-iteration address VALU).
    #define COMPUTE(BUF, KT) do {                                                 \
        short8 mf0 = *(const short8*)(mk + (KT) * 64 + quad * 8);                 \
        short8 mf1 = *(const short8*)(mk + (KT) * 64 + 32 + quad * 8);            \
        _Pragma("unroll")                                                         \
        for (int nt = 0; nt < 4; ++nt) {                                          \
            short8 kf0 = *(const short8*)&Kb[BUF][(nt * 16 + ln) * 64 + kx0];     \
            short8 kf1 = *(const short8*)&Kb[BUF][(nt * 16 + ln) * 64 + kx1];     \
            _Pragma("unroll")                                                     \
            for (int set = 0; set < 2; ++set) {                                   \
                f32x4 z = {0.f, 0.f, 0.f, 0.f};                                   \
                z = MFMA(kf0, qf[set][0], z);                                     \
                z = MFMA(kf1, qf[set][1], z);                                     \
                float p0 = EXP2(z[0]);                                            \
                float p1 = EXP2(z[1]);                                            \
                float p2 = EXP2(z[2]);                                            \
                float p3 = EXP2(z[3]);                                            \
                uint2 w; w.x = packbf2(p0, p1); w.y = packbf2(p2, p3);            \
                *(uint2*)&sPw[(set * 16 + ln) * 64 + (pw0 ^ (nt * 2 << 3)) + pwb] = w; \
            }                                                                     \
        }                                                                         \
        asm volatile("s_waitcnt lgkmcnt(0)" ::: "memory");                        \
        __builtin_amdgcn_s_setprio(1);                                            \
        short8 pf[2][2];                                                          \
        _Pragma("unroll")                                                         \
        for (int set = 0; set < 2; ++set) {                                       \
            pf[set][0] = *(const short8*)&sPw[(set * 16 + ln) * 64 + kx0];        \
            pf[set][1] = *(const short8*)&sPw[(set * 16 + ln) * 64 + kx1];        \
        }                                                                         \
        _Pragma("unroll")                                                         \
        for (int set = 0; set < 2; ++set) {                                       \
            ol[set] = MFMA(pf[set][0], mf0, ol[set]);                             \
            ol[set] = MFMA(pf[set][1], mf1, ol[set]);                             \
        }                                                                         \
        _Pragma("unroll")                                                         \
        for (int dt = 0; dt < 4; ++dt) {                                          \
            short8 vf0 = *(const short8*)&Vb[BUF][(dt * 16 + ln) * 64 + kx0];     \
            short8 vf1 = *(const short8*)&Vb[BUF][(dt * 16 + ln) * 64 + kx1];     \
            _Pragma("unroll")                                                     \
            for (int set = 0; set < 2; ++set) {                                   \
                o[set][dt] = MFMA(pf[set][0], vf0, o[set][dt]);                   \
                o[set][dt] = MFMA(pf[set][1], vf1, o[set][dt]);                   \
            }                                                                     \
        }                                                                         \
        __builtin_amdgcn_s_setprio(0);                                            \
    } while (0)

    STAGE(0, 0);
    __syncthreads();                       // drains vmcnt -> tile 0 ready

    #pragma unroll 1
    for (int kt = 0; kt < SEQ / 64; kt += 2) {
        STAGE(1, kt + 1);                  // async prefetch (kt+1 <= 31 always)
        COMPUTE(0, kt);
        __syncthreads();                   // prefetch landed, all buf0 reads done
        if (kt + 2 < SEQ / 64) STAGE(0, kt + 2);
        COMPUTE(1, kt + 1);
        __syncthreads();
    }
    #undef STAGE
    #undef COMPUTE

    // ---- normalize own rows and write (ol[set][a] aligns with o[set][dt][a]) ----
    #pragma unroll
    for (int set = 0; set < 2; ++set)
        #pragma unroll
        for (int a = 0; a < 4; ++a) {
            float inv = 1.0f / ol[set][a];
            size_t row = (size_t)(n * SEQ + qt * 128 + wave * 32 + set * 16 + quad * 4 + a);
            #pragma unroll
            for (int dt = 0; dt < 4; ++dt)
                A[row * EMB + h * HD + dt * 16 + ln] = f2bf(o[set][dt][a] * inv);
        }
}

// ---------------------------------------------------------------------------
// Kernel 3: out = A @ Wo^T + bo, 128x128 tile, flash-style async pipeline
// (r10; neutral vs r9 but structurally cleaner).  global_load_lds dbuf,
// one barrier per kc, XOR-chunk swizzle.
// grid (EMB/128, NB*SEQ/128), block 256 (2x2 waves of 64x64).
// ---------------------------------------------------------------------------
__global__ __launch_bounds__(256) void outproj_kernel(
    const unsigned short* __restrict__ A, const unsigned short* __restrict__ Wob,
    const float* __restrict__ bo, float* __restrict__ Out)
{
    const int ct = blockIdx.x;   // 128-col tile
    const int rt = blockIdx.y;   // 128-row tile

    const int tid  = threadIdx.x;
    const int wave = tid >> 6, lane = tid & 63;
    const int ln   = lane & 15, quad = lane >> 4;
    const int ln7  = lane & 7;
    const int wm   = wave >> 1, wn = wave & 1;

    __shared__ __align__(16) unsigned short sA[2][128 * 64];   // 16 KiB each
    __shared__ __align__(16) unsigned short sB[2][128 * 64];

    const int r8  = lane >> 3;                       // 0..7
    const int swz = ((lane & 7) ^ r8) << 3;          // shorts within row

    f32x4 acc[4][4];
    #pragma unroll
    for (int i = 0; i < 4; ++i)
        #pragma unroll
        for (int j = 0; j < 4; ++j) acc[i][j] = (f32x4){0.f, 0.f, 0.f, 0.f};

    #define STAGE(buf, kc_) do {                                                  \
        _Pragma("unroll")                                                         \
        for (int sub = 0; sub < 4; ++sub) {                                       \
            int rloc = wave * 32 + sub * 8;                                       \
            gload16(A   + (size_t)(rt * 128 + rloc + r8) * EMB + (kc_) * 64 + swz,\
                    &sA[buf][rloc * 64]);                                         \
            gload16(Wob + (size_t)(ct * 128 + rloc + r8) * EMB + (kc_) * 64 + swz,\
                    &sB[buf][rloc * 64]);                                         \
        }                                                                         \
    } while (0)

    #define COMPUTE(BUF) do {                                                     \
        _Pragma("unroll")                                                         \
        for (int ks = 0; ks < 2; ++ks) {                                          \
            short8 af[4], bf[4];                                                  \
            _Pragma("unroll")                                                     \
            for (int i = 0; i < 4; ++i)                                           \
                af[i] = *(const short8*)&sA[BUF][(wm * 64 + i * 16 + ln) * 64     \
                                                + (((ks * 4 + quad) ^ ln7) << 3)];\
            _Pragma("unroll")                                                     \
            for (int j = 0; j < 4; ++j)                                           \
                bf[j] = *(const short8*)&sB[BUF][(wn * 64 + j * 16 + ln) * 64     \
                                                + (((ks * 4 + quad) ^ ln7) << 3)];\
            _Pragma("unroll")                                                     \
            for (int i = 0; i < 4; ++i)                                           \
                _Pragma("unroll")                                                 \
                for (int j = 0; j < 4; ++j)                                       \
                    acc[i][j] = MFMA(af[i], bf[j], acc[i][j]);                    \
        }                                                                         \
    } while (0)

    STAGE(0, 0);
    __syncthreads();                       // drains vmcnt -> tile 0 ready

    #pragma unroll 1
    for (int kc = 0; kc < EMB / 64; kc += 2) {
        STAGE(1, kc + 1);                  // async prefetch
        COMPUTE(0);
        __syncthreads();                   // prefetch landed, all buf0 reads done
        if (kc + 2 < EMB / 64) STAGE(0, kc + 2);
        COMPUTE(1);
        __syncthreads();
    }
    #undef STAGE
    #undef COMPUTE

    #pragma unroll
    for (int j = 0; j < 4; ++j) {
        int col = ct * 128 + wn * 64 + j * 16 + ln;
        float bb = bo[col];
        #pragma unroll
        for (int i = 0; i < 4; ++i)
            #pragma unroll
            for (int a = 0; a < 4; ++a) {
                size_t row = (size_t)(rt * 128 + wm * 64 + i * 16 + quad * 4 + a);
                Out[row * EMB + col] = acc[i][j][a] + bb;
            }
    }
}

// ---------------------------------------------------------------------------
extern "C" void kernel_launch(void* const* d_in, const int* in_sizes, int n_in,
                              void* d_out, int out_size, void* d_ws, size_t ws_size,
                              hipStream_t stream) {
    const float* values = (const float*)d_in[0];
    const float* key_   = (const float*)d_in[1];
    const float* query  = (const float*)d_in[2];
    const int*   mask   = (const int*)d_in[3];
    const float* Wv     = (const float*)d_in[4];
    const float* Wk     = (const float*)d_in[5];
    const float* Wq     = (const float*)d_in[6];
    const float* bq     = (const float*)d_in[7];
    const float* Wo     = (const float*)d_in[8];
    const float* bo     = (const float*)d_in[9];
    float* out = (float*)d_out;

    const size_t NHLD = (size_t)NB * NH * SEQ * HD;   // 4,194,304

    unsigned short* ws = (unsigned short*)d_ws;
    unsigned short* Qp    = ws;
    unsigned short* Kp    = ws + NHLD;
    unsigned short* Vtp   = ws + 2 * NHLD;
    unsigned short* Aattn = ws + 3 * NHLD;
    unsigned short* Wob   = ws + 4 * NHLD;                  // EMB*EMB
    unsigned short* Mb    = Wob + (size_t)EMB * EMB;        // NB*SEQ bf16 mask

    qkv_kernel<<<dim3(SEQ / 128, NH, 3 * NB), 256, 0, stream>>>(
        query, key_, values, Wq, Wk, Wv, bq, mask, Wo, Wob, Mb, Qp, Kp, Vtp);
    flash_kernel<<<dim3(NB * NH, SEQ / 128), 256, 0, stream>>>(
        Qp, Kp, Vtp, Mb, Aattn);
    outproj_kernel<<<dim3(EMB / 128, NB * SEQ / 128), 256, 0, stream>>>(
        Aattn, Wob, bo, out);
}